// Round 10
// baseline (372.636 us; speedup 1.0000x reference)
//
#include <hip/hip_runtime.h>

typedef __attribute__((ext_vector_type(8))) short short8;
typedef __attribute__((ext_vector_type(16))) float f32x16;
typedef unsigned short ushort_t;

#define BAR()   __builtin_amdgcn_s_barrier()
#define VM0()   asm volatile("s_waitcnt vmcnt(0)" ::: "memory")
#define MFMA32(a_, b_, c_) __builtin_amdgcn_mfma_f32_32x32x16_bf16(a_, b_, c_, 0, 0, 0)

// ---------- helpers ----------
__device__ __forceinline__ unsigned short f2bf(float f) {
  unsigned u = __builtin_bit_cast(unsigned, f);
  u += 0x7FFFu + ((u >> 16) & 1u);   // round-to-nearest-even
  return (unsigned short)(u >> 16);
}

__device__ __forceinline__ void gl_lds16(const void* g, void* l) {
  __builtin_amdgcn_global_load_lds(
      (const __attribute__((address_space(1))) void*)g,
      (__attribute__((address_space(3))) void*)l, 16, 0, 0);
}

// ---------- kernel 1: x (f32) -> bf16 ----------
__global__ __launch_bounds__(256) void cvt_x(const float* __restrict__ x,
                                             ushort_t* __restrict__ xb) {
  size_t i = ((size_t)blockIdx.x * 256 + threadIdx.x) * 8;
  float4 v0 = *(const float4*)(x + i);
  float4 v1 = *(const float4*)(x + i + 4);
  union { ushort_t s[8]; uint4 v; } o;
  o.s[0] = f2bf(v0.x); o.s[1] = f2bf(v0.y); o.s[2] = f2bf(v0.z); o.s[3] = f2bf(v0.w);
  o.s[4] = f2bf(v1.x); o.s[5] = f2bf(v1.y); o.s[6] = f2bf(v1.z); o.s[7] = f2bf(v1.w);
  *(uint4*)(xb + i) = o.v;
}

// ---------- kernel 2: W_eff = W + A@B, stored bf16 ----------
__global__ __launch_bounds__(256) void build_weff(const float* __restrict__ W,
                                                  const float* __restrict__ A,
                                                  const float* __restrict__ B,
                                                  ushort_t* __restrict__ Weff) {
  const int K = 4096, R = 16;
  const int n = blockIdx.y;
  const int k = (blockIdx.x * 256 + threadIdx.x) * 4;
  float4 w = *(const float4*)(W + (size_t)n * K + k);
  float a0 = w.x, a1 = w.y, a2 = w.z, a3 = w.w;
#pragma unroll
  for (int r = 0; r < R; ++r) {
    float a = A[n * R + r];
    float4 b = *(const float4*)(B + (size_t)r * K + k);
    a0 += a * b.x; a1 += a * b.y; a2 += a * b.z; a3 += a * b.w;
  }
  union { ushort_t s[4]; uint2 v; } o;
  o.s[0] = f2bf(a0); o.s[1] = f2bf(a1); o.s[2] = f2bf(a2); o.s[3] = f2bf(a3);
  *(uint2*)(Weff + (size_t)n * K + k) = o.v;
}

// ---------- kernel 3: 256x256 bf16 GEMM, 4 waves x 128x128/wave ----------
// C[M][N] = Xb[M][K] * Wb[N][K]^T. BM=BN=256, BK=64. 4 waves (2M x 2N),
// per-wave C = 128x128 = acc[4][4] f32x16; 64 MFMA(32x32x16)/wave/K-tile.
// WHY 4 waves: per-wave LDS reads = (mi+ni)*4 b128, MFMA = mi*ni*4.
//   8 waves (4,2): 192 reads/CU/tile = 2304 cy LDS pipe (> MFMA 2066) -> LDS-bound.
//   4 waves (4,4): 128 reads/CU/tile = 1536 cy; MFMA 2066 -> MFMA-bound.
// 1 wave/SIMD: no cross-wave lockstep; overlap via compiler's counted-lgkmcnt
// interleave of ds_read/MFMA within the barrier interval. Separate operand
// regs per k-half (a0/b0 vs a1/b1) so kh1 reads issue during kh0 MFMAs.
// VGPR: acc 256 + operands 128 + addr ~25 = ~410 < 512 @ 1 wave/SIMD.
// LDS [2 dbuf][A-k0,A-k1,B-k0,B-k1][256r][32c] bf16 = 128 KiB (1 block/CU).
// Swizzle (round-9 MEASURED ZERO): phys col byte = logical ^ row3<<5 ^ row4<<4;
// pre-swizzled global source + linear LDS dest (rule 21) + same XOR on read.
// Schedule (round-5-verified strict dbuf, 1 barrier/tile):
//   stage t+1 -> cur^1 (16 gl_lds); read kh0+kh1 (32 b128); 64 MFMA; VM0; BAR.

__device__ __forceinline__ void stage_half(const ushort_t* __restrict__ G, int row0, int kc,
                                           ushort_t* half, int tid) {
#pragma unroll
  for (int r = 0; r < 4; ++r) {
    const int idx  = r * 256 + tid;                               // 0..1023
    const int lrow = idx >> 2;                                    // 0..255
    const int cb   = ((idx & 3) * 16) ^ (((lrow >> 3) & 1) << 5)
                                      ^ (((lrow >> 4) & 1) << 4); // pre-swizzled source col
    const ushort_t* src = G + (size_t)(row0 + lrow) * 4096 + kc + (cb >> 1);
    char* dst = (char*)half + (size_t)(r * 256 + (tid & ~63)) * 16; // wave-uniform; HW adds lane*16
    gl_lds16(src, dst);
  }
}

__global__ __launch_bounds__(256, 1) void gemm256(const ushort_t* __restrict__ Xb,
                                                  const ushort_t* __restrict__ Wb,
                                                  float* __restrict__ C) {
  const int N = 4096;
  const int NT = 4096 / 64;                 // 64 K-tiles
  __shared__ __align__(16) ushort_t lds[2][4][256 * 32];  // [buf][A-k0,A-k1,B-k0,B-k1]

  const int tid = threadIdx.x;
  const int l   = tid & 63;
  const int w   = tid >> 6;                 // 0..3
  const int wm  = w >> 1;                   // 0..1
  const int wn  = w & 1;                    // 0..1

  // T1: bijective XCD chunking — 512 blocks = 8 chunks of 8x8 tiles (grid 32x16)
  const int bid = blockIdx.x;
  const int c = bid & 7, q = bid >> 3;
  const int tm = (c >> 1) * 8 + (q >> 3);   // 0..31
  const int tn = (c & 1) * 8 + (q & 7);     // 0..15
  const int bm = tm * 256, bn = tn * 256;

  // fragment byte offsets in a [256][32] half (2-bit swizzled read side).
  // row stride 64 B; lane row = l&31; k-chunk byte = (l>>5)*16; ks slice = ^32.
  const int colb0 = ((l >> 5) * 16) ^ (((l >> 3) & 1) << 5) ^ (((l >> 4) & 1) << 4);
  int aoff[4], boff[4];
#pragma unroll
  for (int mi = 0; mi < 4; ++mi) aoff[mi] = (wm * 128 + mi * 32 + (l & 31)) * 64 + colb0;
#pragma unroll
  for (int ni = 0; ni < 4; ++ni) boff[ni] = (wn * 128 + ni * 32 + (l & 31)) * 64 + colb0;

  f32x16 acc[4][4];
#pragma unroll
  for (int i = 0; i < 4; ++i)
#pragma unroll
    for (int j = 0; j < 4; ++j) acc[i][j] = (f32x16)(0.0f);

  // prologue: stage tile 0 into buf 0, drain, barrier
  stage_half(Wb, bn, 0,  lds[0][2], tid);
  stage_half(Xb, bm, 0,  lds[0][0], tid);
  stage_half(Wb, bn, 32, lds[0][3], tid);
  stage_half(Xb, bm, 32, lds[0][1], tid);
  VM0();
  BAR();

  short8 a0[4][2], b0[4][2];   // kh0 operands
  short8 a1[4][2], b1[4][2];   // kh1 operands (separate regs -> reads overlap kh0 MFMA)

#define RD(P_) (*(const short8*)(P_))

  int cur = 0;
  for (int t = 0; t < NT; ++t) {
    const char* A0h = (const char*)lds[cur][0];
    const char* A1h = (const char*)lds[cur][1];
    const char* B0h = (const char*)lds[cur][2];
    const char* B1h = (const char*)lds[cur][3];

    // stage tile t+1 into buf cur^1 (16 issues; drained at VM0 below)
    if (t + 1 < NT) {
      const int kc = (t + 1) * 64;
      stage_half(Wb, bn, kc,      lds[cur ^ 1][2], tid);
      stage_half(Xb, bm, kc,      lds[cur ^ 1][0], tid);
      stage_half(Wb, bn, kc + 32, lds[cur ^ 1][3], tid);
      stage_half(Xb, bm, kc + 32, lds[cur ^ 1][1], tid);
    }

    // reads: kh0 then kh1 (32 b128); compiler interleaves with MFMAs via lgkmcnt
#pragma unroll
    for (int mi = 0; mi < 4; ++mi)
#pragma unroll
      for (int ks = 0; ks < 2; ++ks) a0[mi][ks] = RD(A0h + (aoff[mi] ^ (ks << 5)));
#pragma unroll
    for (int ni = 0; ni < 4; ++ni)
#pragma unroll
      for (int ks = 0; ks < 2; ++ks) b0[ni][ks] = RD(B0h + (boff[ni] ^ (ks << 5)));
#pragma unroll
    for (int mi = 0; mi < 4; ++mi)
#pragma unroll
      for (int ks = 0; ks < 2; ++ks) a1[mi][ks] = RD(A1h + (aoff[mi] ^ (ks << 5)));
#pragma unroll
    for (int ni = 0; ni < 4; ++ni)
#pragma unroll
      for (int ks = 0; ks < 2; ++ks) b1[ni][ks] = RD(B1h + (boff[ni] ^ (ks << 5)));

    // 64 MFMA: kh0 (32) then kh1 (32)
#pragma unroll
    for (int ks = 0; ks < 2; ++ks)
#pragma unroll
      for (int mi = 0; mi < 4; ++mi)
#pragma unroll
        for (int ni = 0; ni < 4; ++ni)
          acc[mi][ni] = MFMA32(a0[mi][ks], b0[ni][ks], acc[mi][ni]);
#pragma unroll
    for (int ks = 0; ks < 2; ++ks)
#pragma unroll
      for (int mi = 0; mi < 4; ++mi)
#pragma unroll
        for (int ni = 0; ni < 4; ++ni)
          acc[mi][ni] = MFMA32(a1[mi][ks], b1[ni][ks], acc[mi][ni]);

    VM0();          // tile t+1 fully landed in cur^1 (issued ~3000 cy earlier)
    BAR();          // all waves done reading cur
    cur ^= 1;
  }

  // epilogue: 32x32 C/D layout col = l&31, row = (reg&3) + 8*(reg>>2) + 4*(l>>5)
  const int erow0 = bm + wm * 128 + 4 * (l >> 5);
  const int ecol  = bn + wn * 128 + (l & 31);
#pragma unroll
  for (int mi = 0; mi < 4; ++mi) {
#pragma unroll
    for (int ni = 0; ni < 4; ++ni) {
      float* cp = C + (size_t)(erow0 + mi * 32) * N + ecol + ni * 32;
#pragma unroll
      for (int r = 0; r < 16; ++r)
        cp[(size_t)((r & 3) + 8 * (r >> 2)) * N] = acc[mi][ni][r];
    }
  }
}

extern "C" void kernel_launch(void* const* d_in, const int* in_sizes, int n_in,
                              void* d_out, int out_size, void* d_ws, size_t ws_size,
                              hipStream_t stream) {
  const float* x = (const float*)d_in[0];   // [8192, 4096]
  const float* W = (const float*)d_in[1];   // [4096, 4096]
  const float* A = (const float*)d_in[2];   // [4096, 16]
  const float* B = (const float*)d_in[3];   // [16, 4096]
  float* out = (float*)d_out;               // [8192, 4096]

  ushort_t* xb = (ushort_t*)d_ws;                                    // 64 MB
  ushort_t* wb = (ushort_t*)((char*)d_ws + (size_t)8192 * 4096 * 2); // 32 MB

  cvt_x<<<16384, 256, 0, stream>>>(x, xb);
  dim3 gw(4, 4096);
  build_weff<<<gw, 256, 0, stream>>>(W, A, B, wb);
  gemm256<<<512, 256, 0, stream>>>(xb, wb, out);  // grid 32x16 tiles, XCD-chunked
}

// Round 11
// 354.879 us; speedup vs baseline: 1.0500x; 1.0500x over previous
//
#include <hip/hip_runtime.h>

typedef __attribute__((ext_vector_type(8))) short short8;
typedef __attribute__((ext_vector_type(4))) float f32x4;
typedef unsigned short ushort_t;

#define BAR()   __builtin_amdgcn_s_barrier()
#define LGKM0() asm volatile("s_waitcnt lgkmcnt(0)" ::: "memory")
#define VM6()   asm volatile("s_waitcnt vmcnt(6)" ::: "memory")
#define VM0()   asm volatile("s_waitcnt vmcnt(0)" ::: "memory")
#define PRIO(n) __builtin_amdgcn_s_setprio(n)
#define MFMA(a_, b_, c_) __builtin_amdgcn_mfma_f32_16x16x32_bf16(a_, b_, c_, 0, 0, 0)

// ---------- helpers ----------
__device__ __forceinline__ unsigned short f2bf(float f) {
  unsigned u = __builtin_bit_cast(unsigned, f);
  u += 0x7FFFu + ((u >> 16) & 1u);   // round-to-nearest-even
  return (unsigned short)(u >> 16);
}

__device__ __forceinline__ void gl_lds16(const void* g, void* l) {
  __builtin_amdgcn_global_load_lds(
      (const __attribute__((address_space(1))) void*)g,
      (__attribute__((address_space(3))) void*)l, 16, 0, 0);
}

// ---------- kernel 1: x (f32) -> bf16 ----------
__global__ __launch_bounds__(256) void cvt_x(const float* __restrict__ x,
                                             ushort_t* __restrict__ xb) {
  size_t i = ((size_t)blockIdx.x * 256 + threadIdx.x) * 8;
  float4 v0 = *(const float4*)(x + i);
  float4 v1 = *(const float4*)(x + i + 4);
  union { ushort_t s[8]; uint4 v; } o;
  o.s[0] = f2bf(v0.x); o.s[1] = f2bf(v0.y); o.s[2] = f2bf(v0.z); o.s[3] = f2bf(v0.w);
  o.s[4] = f2bf(v1.x); o.s[5] = f2bf(v1.y); o.s[6] = f2bf(v1.z); o.s[7] = f2bf(v1.w);
  *(uint4*)(xb + i) = o.v;
}

// ---------- kernel 2: W_eff = W + A@B, stored bf16 (8 elems/thread) ----------
__global__ __launch_bounds__(256) void build_weff(const float* __restrict__ W,
                                                  const float* __restrict__ A,
                                                  const float* __restrict__ B,
                                                  ushort_t* __restrict__ Weff) {
  const int K = 4096, R = 16;
  const int n = blockIdx.y;
  const int k = (blockIdx.x * 256 + threadIdx.x) * 8;
  float4 w0 = *(const float4*)(W + (size_t)n * K + k);
  float4 w1 = *(const float4*)(W + (size_t)n * K + k + 4);
  float s0 = w0.x, s1 = w0.y, s2 = w0.z, s3 = w0.w;
  float s4 = w1.x, s5 = w1.y, s6 = w1.z, s7 = w1.w;
#pragma unroll
  for (int r = 0; r < R; ++r) {
    float a = A[n * R + r];                       // uniform per block -> scalar load
    float4 b0 = *(const float4*)(B + (size_t)r * K + k);
    float4 b1 = *(const float4*)(B + (size_t)r * K + k + 4);
    s0 += a * b0.x; s1 += a * b0.y; s2 += a * b0.z; s3 += a * b0.w;
    s4 += a * b1.x; s5 += a * b1.y; s6 += a * b1.z; s7 += a * b1.w;
  }
  union { ushort_t s[8]; uint4 v; } o;
  o.s[0] = f2bf(s0); o.s[1] = f2bf(s1); o.s[2] = f2bf(s2); o.s[3] = f2bf(s3);
  o.s[4] = f2bf(s4); o.s[5] = f2bf(s5); o.s[6] = f2bf(s6); o.s[7] = f2bf(s7);
  *(uint4*)(Weff + (size_t)n * K + k) = o.v;      // 16 B/lane store
}

// ---------- kernel 3: 256x256 8-phase bf16 GEMM (round-4 champion, verbatim) ----------
// Measured (round 4): 250 us, MfmaUtil 50-51%, SQ_LDS_BANK_CONFLICT = 0.
// C[M][N] = Xb[M][K] * Wb[N][K]^T. BM=BN=256, BK=64 (2 k-halves of 32).
// LDS: 2 dbuf x 4 halves (A-k0, A-k1, B-k0, B-k1) x [256 rows][32 cols] bf16 = 128 KiB.
// 8 waves (2M x 4N); per-wave C = 128x64 = acc[8][4] f32x4.
// Per K-tile 4 phases: P1{rd a0-3/k0 + b0-3/k0, stage A-k1(t+1)->buf^1}  Q(m0-3,k0)
//                      P2{rd a4-7/k0,            stage B-k0(t+2)->buf}    Q(m4-7,k0)
//                      P3{rd a0-3/k1 + b0-3/k1,  stage A-k0(t+2)->buf}    Q(m0-3,k1)
//                      P4{rd a4-7/k1,            stage B-k1(t+2)->buf, vmcnt(6)} Q(m4-7,k1)
// vmcnt(6) = 3 half-tiles (2 loads each) in flight; tile t+1 fully landed at its BAR.
// st_16x32 swizzle: byte^=((row>>3)&1)<<5, pre-swizzled global SOURCE at stage +
// same XOR on ds_read addr; LDS dest linear for global_load_lds (rule 21).

__device__ __forceinline__ void stage_half(const ushort_t* __restrict__ G, int row0, int kc,
                                           ushort_t* half, int tid) {
#pragma unroll
  for (int r = 0; r < 2; ++r) {
    const int idx  = r * 512 + tid;
    const int lrow = idx >> 2;                                  // 0..255
    const int cb   = ((idx & 3) * 16) ^ (((lrow >> 3) & 1) << 5); // pre-swizzled source col (bytes)
    const ushort_t* src = G + (size_t)(row0 + lrow) * 4096 + kc + (cb >> 1);
    char* dst = (char*)half + (size_t)(r * 512 + (tid & ~63)) * 16; // wave-uniform; HW adds lane*16
    gl_lds16(src, dst);
  }
}

__global__ __launch_bounds__(512, 2) void gemm256(const ushort_t* __restrict__ Xb,
                                                  const ushort_t* __restrict__ Wb,
                                                  float* __restrict__ C) {
  const int N = 4096;
  const int NT = 4096 / 64;                 // 64 K-tiles
  __shared__ __align__(16) ushort_t lds[2][4][256 * 32];  // [buf][A0,A1,B0,B1][row][col]

  const int tid = threadIdx.x;
  const int l   = tid & 63;
  const int w   = tid >> 6;
  const int wm  = w >> 2;                   // 0..1
  const int wn  = w & 3;                    // 0..3

  // T1: bijective XCD chunking — 512 blocks = 8 chunks of 8x8 tiles (grid 32x16)
  const int bid = blockIdx.x;
  const int c = bid & 7, q = bid >> 3;
  const int tm = (c >> 1) * 8 + (q >> 3);   // 0..31
  const int tn = (c & 1) * 8 + (q & 7);     // 0..15
  const int bm = tm * 256, bn = tn * 256;

  // fragment LDS byte offsets within a half (swizzled read side)
  const int colb = ((l >> 4) * 16) ^ (((l >> 3) & 1) << 5);
  int aoff[8], boff[4];
#pragma unroll
  for (int mi = 0; mi < 8; ++mi) aoff[mi] = (wm * 128 + mi * 16 + (l & 15)) * 64 + colb;
#pragma unroll
  for (int ni = 0; ni < 4; ++ni) boff[ni] = (wn * 64 + ni * 16 + (l & 15)) * 64 + colb;

  f32x4 acc[8][4];
#pragma unroll
  for (int i = 0; i < 8; ++i)
#pragma unroll
    for (int j = 0; j < 4; ++j) acc[i][j] = (f32x4)(0.0f);

  // prologue: 7 halves (tile0 all + tile1 B-k0,A-k0,B-k1), then vmcnt(6) -> tile0 landed
  stage_half(Wb, bn, 0,  lds[0][2], tid);
  stage_half(Xb, bm, 0,  lds[0][0], tid);
  stage_half(Wb, bn, 32, lds[0][3], tid);
  stage_half(Xb, bm, 32, lds[0][1], tid);
  stage_half(Wb, bn, 64, lds[1][2], tid);
  stage_half(Xb, bm, 64, lds[1][0], tid);
  stage_half(Wb, bn, 96, lds[1][3], tid);
  VM6();
  BAR();

  short8 af0, af1, af2, af3, bf0, bf1, bf2, bf3;

#define LDA(P_, I0_) do { \
    af0 = *(const short8*)((const char*)(P_) + aoff[(I0_) + 0]); \
    af1 = *(const short8*)((const char*)(P_) + aoff[(I0_) + 1]); \
    af2 = *(const short8*)((const char*)(P_) + aoff[(I0_) + 2]); \
    af3 = *(const short8*)((const char*)(P_) + aoff[(I0_) + 3]); \
  } while (0)
#define LDB(P_) do { \
    bf0 = *(const short8*)((const char*)(P_) + boff[0]); \
    bf1 = *(const short8*)((const char*)(P_) + boff[1]); \
    bf2 = *(const short8*)((const char*)(P_) + boff[2]); \
    bf3 = *(const short8*)((const char*)(P_) + boff[3]); \
  } while (0)
#define QUAD(M0_) do { \
    acc[(M0_)+0][0] = MFMA(af0, bf0, acc[(M0_)+0][0]); \
    acc[(M0_)+0][1] = MFMA(af0, bf1, acc[(M0_)+0][1]); \
    acc[(M0_)+0][2] = MFMA(af0, bf2, acc[(M0_)+0][2]); \
    acc[(M0_)+0][3] = MFMA(af0, bf3, acc[(M0_)+0][3]); \
    acc[(M0_)+1][0] = MFMA(af1, bf0, acc[(M0_)+1][0]); \
    acc[(M0_)+1][1] = MFMA(af1, bf1, acc[(M0_)+1][1]); \
    acc[(M0_)+1][2] = MFMA(af1, bf2, acc[(M0_)+1][2]); \
    acc[(M0_)+1][3] = MFMA(af1, bf3, acc[(M0_)+1][3]); \
    acc[(M0_)+2][0] = MFMA(af2, bf0, acc[(M0_)+2][0]); \
    acc[(M0_)+2][1] = MFMA(af2, bf1, acc[(M0_)+2][1]); \
    acc[(M0_)+2][2] = MFMA(af2, bf2, acc[(M0_)+2][2]); \
    acc[(M0_)+2][3] = MFMA(af2, bf3, acc[(M0_)+2][3]); \
    acc[(M0_)+3][0] = MFMA(af3, bf0, acc[(M0_)+3][0]); \
    acc[(M0_)+3][1] = MFMA(af3, bf1, acc[(M0_)+3][1]); \
    acc[(M0_)+3][2] = MFMA(af3, bf2, acc[(M0_)+3][2]); \
    acc[(M0_)+3][3] = MFMA(af3, bf3, acc[(M0_)+3][3]); \
  } while (0)

  int cur = 0;
  for (int t = 0; t < NT; ++t) {
    const ushort_t* A0h = lds[cur][0];
    const ushort_t* A1h = lds[cur][1];
    const ushort_t* B0h = lds[cur][2];
    const ushort_t* B1h = lds[cur][3];
    const int kc2 = (t + 2) * 64;

    // P1
    LDA(A0h, 0); LDB(B0h);
    if (t + 1 < NT) stage_half(Xb, bm, (t + 1) * 64 + 32, lds[cur ^ 1][1], tid);
    BAR(); LGKM0(); PRIO(1);
    QUAD(0);
    PRIO(0); BAR();

    // P2
    LDA(A0h, 4);
    if (t + 2 < NT) stage_half(Wb, bn, kc2, lds[cur][2], tid);
    BAR(); LGKM0(); PRIO(1);
    QUAD(4);
    PRIO(0); BAR();

    // P3
    LDA(A1h, 0); LDB(B1h);
    if (t + 2 < NT) stage_half(Xb, bm, kc2, lds[cur][0], tid);
    BAR(); LGKM0(); PRIO(1);
    QUAD(0);
    PRIO(0); BAR();

    // P4
    LDA(A1h, 4);
    if (t + 2 < NT) stage_half(Wb, bn, kc2 + 32, lds[cur][3], tid);
    if (t + 2 < NT) { VM6(); } else { VM0(); }
    BAR(); LGKM0(); PRIO(1);
    QUAD(4);
    PRIO(0); BAR();

    cur ^= 1;
  }

  // epilogue: C/D layout col = lane&15, row = (lane>>4)*4 + j
  const int erow = bm + wm * 128 + (l >> 4) * 4;
  const int ecol = bn + wn * 64 + (l & 15);
#pragma unroll
  for (int mi = 0; mi < 8; ++mi) {
#pragma unroll
    for (int ni = 0; ni < 4; ++ni) {
      float* cp = C + (size_t)(erow + mi * 16) * N + ecol + ni * 16;
#pragma unroll
      for (int j = 0; j < 4; ++j) cp[(size_t)j * N] = acc[mi][ni][j];
    }
  }
}

extern "C" void kernel_launch(void* const* d_in, const int* in_sizes, int n_in,
                              void* d_out, int out_size, void* d_ws, size_t ws_size,
                              hipStream_t stream) {
  const float* x = (const float*)d_in[0];   // [8192, 4096]
  const float* W = (const float*)d_in[1];   // [4096, 4096]
  const float* A = (const float*)d_in[2];   // [4096, 16]
  const float* B = (const float*)d_in[3];   // [16, 4096]
  float* out = (float*)d_out;               // [8192, 4096]

  ushort_t* xb = (ushort_t*)d_ws;                                    // 64 MB
  ushort_t* wb = (ushort_t*)((char*)d_ws + (size_t)8192 * 4096 * 2); // 32 MB

  cvt_x<<<16384, 256, 0, stream>>>(x, xb);
  dim3 gw(2, 4096);
  build_weff<<<gw, 256, 0, stream>>>(W, A, B, wb);
  gemm256<<<512, 512, 0, stream>>>(xb, wb, out);  // grid 32x16 tiles, XCD-chunked
}